// Round 4
// baseline (552.446 us; speedup 1.0000x reference)
//
#include <hip/hip_runtime.h>

// Problem dims
#define B_  32
#define N_  1024
#define E_  1024
#define H_  8
#define D_  128
#define MID_ 64
#define NT_  4         // n-tiles for fused score+pool (256 rows each)
#define NS2_ 8         // n-splits for v2 pooling

// All inputs are float32 (verified: threshold = 2%*max|ref| with no bf16 floor
// => _any_bf16 false). Output is float32 (reference returns jnp.float32).

// ---------------------------------------------------------------------------
// K1: per (b,h): Q[d] = query[b]·Wq_row(h*D+d) + bq ; qb[b,h] = Q·bk_slice
//     qk[b,h,e] = sum_d Q[d] * Wk[h*D+d, e]
// grid 256 blocks (b*8+h), 256 threads
// ---------------------------------------------------------------------------
__global__ __launch_bounds__(256) void k_qkproj(
        const float* __restrict__ query, const float* __restrict__ Wq,
        const float* __restrict__ bq, const float* __restrict__ Wk,
        const float* __restrict__ bk, float* __restrict__ qk,
        float* __restrict__ qb)
{
    const int bh = blockIdx.x;
    const int b = bh >> 3, h = bh & 7;
    const int t = threadIdx.x;

    __shared__ float Qp[2][D_];
    __shared__ float Qs[D_];
    __shared__ float red[2];

    // phase A: Q slice, 2 threads per d (e split in halves of 512)
    {
        const int d = t & 127, half = t >> 7;
        const int row = h * D_ + d;
        const float4* wr = (const float4*)(Wq + (size_t)row * E_) + half * 128;
        const float4* qr = (const float4*)(query + (size_t)b * E_) + half * 128;
        float acc = 0.f;
        for (int i = 0; i < 128; ++i) {
            float4 w = wr[i], q = qr[i];
            acc += w.x * q.x + w.y * q.y + w.z * q.z + w.w * q.w;
        }
        Qp[half][d] = acc;
    }
    __syncthreads();
    if (t < D_) {
        const int row = h * D_ + t;
        float q = Qp[0][t] + Qp[1][t] + bq[row];
        Qs[t] = q;
        float qp = q * bk[row];
        #pragma unroll
        for (int off = 32; off; off >>= 1) qp += __shfl_down(qp, off);
        if ((t & 63) == 0) red[t >> 6] = qp;
    }
    __syncthreads();
    if (t == 0) qb[bh] = red[0] + red[1];

    // phase B: qk row, thread owns 4 e's (coalesced float4 per d-iteration)
    const int e0 = t * 4;
    float4 a = make_float4(0.f, 0.f, 0.f, 0.f);
    const float* wkb = Wk + (size_t)(h * D_) * E_ + e0;
    for (int d = 0; d < D_; ++d) {
        float Qd = Qs[d];
        float4 w = *(const float4*)(wkb + (size_t)d * E_);
        a.x += Qd * w.x; a.y += Qd * w.y; a.z += Qd * w.z; a.w += Qd * w.w;
    }
    *(float4*)(qk + (size_t)bh * E_ + e0) = a;
}

// ---------------------------------------------------------------------------
// K2 (fused): per (tile,b):
//   phase1: s[n,h] = (key[n]·qk[h] + qb[h]) / sqrt(D) for 256 rows (to LDS),
//           atomicAdd per-h score-sum into ssum[b,h]
//   phase2: atomicAdd PP[b,h,e] += sum_{n in tile} s[n,h]*key[n,e] (key L2-hot)
// grid (NT, B), 256 threads
// ---------------------------------------------------------------------------
__global__ __launch_bounds__(256) void k_scorepool(
        const float* __restrict__ key, const float* __restrict__ qk,
        const float* __restrict__ qb, float* __restrict__ PP,
        float* __restrict__ ssum)
{
    const int tile = blockIdx.x, b = blockIdx.y;
    const int t = threadIdx.x;
    __shared__ float ssc[256][H_];   // 8 KB

    // phase 1: thread = (slot = t>>3 in [0,32), hl = t&7), 8 rows per thread
    {
        const int hl = t & 7, slot = t >> 3;
        const float qbv = qb[b * 8 + hl];
        const float4* qrow = (const float4*)(qk + (size_t)(b * 8 + hl) * E_);
        const float4* kr[8];
        #pragma unroll
        for (int r = 0; r < 8; ++r)
            kr[r] = (const float4*)(key + ((size_t)(b * N_) + tile * 256 + r * 32 + slot) * E_);
        float acc[8] = {};
        for (int i = 0; i < 256; ++i) {
            float4 q = qrow[i];
            #pragma unroll
            for (int r = 0; r < 8; ++r) {
                float4 k4 = kr[r][i];
                acc[r] += q.x * k4.x + q.y * k4.y + q.z * k4.z + q.w * k4.w;
            }
        }
        const float scale = 0.08838834764831845f;  // 1/sqrt(128)
        float ts = 0.f;
        #pragma unroll
        for (int r = 0; r < 8; ++r) {
            int nl = r * 32 + slot;
            float s = (acc[r] + qbv) * scale;
            ssc[nl][hl] = s;
            ts += s;
        }
        // reduce ts over the 8 lanes of this wave sharing hl (stride 8 in lane id)
        ts += __shfl_down(ts, 8);
        ts += __shfl_down(ts, 16);
        ts += __shfl_down(ts, 32);
        if ((t & 63) < 8) atomicAdd(&ssum[b * 8 + hl], ts);
    }
    __syncthreads();

    // phase 2: thread owns 4 e's; loop tile's 256 rows (L2-hot re-read)
    {
        const int e0 = t * 4;
        float p[H_][4] = {};
        const float* kb = key + ((size_t)(b * N_) + tile * 256) * E_ + e0;
        for (int n = 0; n < 256; ++n) {
            float4 kv = *(const float4*)(kb + (size_t)n * E_);
            #pragma unroll
            for (int h = 0; h < H_; ++h) {
                float s = ssc[n][h];
                p[h][0] += s * kv.x; p[h][1] += s * kv.y;
                p[h][2] += s * kv.z; p[h][3] += s * kv.w;
            }
        }
        #pragma unroll
        for (int h = 0; h < H_; ++h) {
            float* dst = PP + ((size_t)(b * H_) + h) * E_ + e0;
            atomicAdd(dst + 0, p[h][0]); atomicAdd(dst + 1, p[h][1]);
            atomicAdd(dst + 2, p[h][2]); atomicAdd(dst + 3, p[h][3]);
        }
    }
}

// ---------------------------------------------------------------------------
// K3: P2[b,e] += sum_{n in split, mask=1} value2[b,n,e]  (atomic over splits)
// grid (NS2, B), 256 threads
// ---------------------------------------------------------------------------
__global__ __launch_bounds__(256) void k_pool_v2(
        const float* __restrict__ value2, const int* __restrict__ mask,
        float* __restrict__ P2)
{
    const int ns = blockIdx.x, b = blockIdx.y;
    const int t = threadIdx.x, e0 = t * 4;
    float a0 = 0.f, a1 = 0.f, a2 = 0.f, a3 = 0.f;
    const int n0 = ns * (N_ / NS2_);
    for (int n = n0; n < n0 + N_ / NS2_; ++n) {
        if (mask[b * N_ + n]) {   // block-uniform branch: skips whole 4KB row
            float4 v = *(const float4*)(value2 + ((size_t)(b * N_ + n)) * E_ + e0);
            a0 += v.x; a1 += v.y; a2 += v.z; a3 += v.w;
        }
    }
    float* dst = P2 + (size_t)b * E_ + e0;
    atomicAdd(dst + 0, a0); atomicAdd(dst + 1, a1);
    atomicAdd(dst + 2, a2); atomicAdd(dst + 3, a3);
}

// ---------------------------------------------------------------------------
// K4: final. per (b,h), 128 threads (thread = d)
//  attended_d = PP[b,h]·Wv_row(h*D+d) + ssum*bv_d
//  hv_m = relu(attended·Wb_m + bb_m)        (h constant over n → mask-pool = h)
//  alphac_d = sigmoid(sum_m hv_m*Wl2[d,m] + bl2_d)
//  v2a_d = P2[b]·Wv_row/cnt + bv_d          (softmax of uniform = mask/cnt)
//  out = f32(v1 * v2a * alphac)
// ---------------------------------------------------------------------------
__global__ __launch_bounds__(128) void k_final(
        const float* __restrict__ PP, const float* __restrict__ P2,
        const float* __restrict__ ssumg, const int* __restrict__ mask,
        const float* __restrict__ Wv, const float* __restrict__ bv,
        const float* __restrict__ Wb, const float* __restrict__ bb,
        const float* __restrict__ Wl2, const float* __restrict__ bl2,
        const float* __restrict__ value1, float* __restrict__ out)
{
    const int bh = blockIdx.x, b = bh >> 3, h = bh & 7;
    const int t = threadIdx.x;

    __shared__ float pooled[E_];
    __shared__ float pool2[E_];
    __shared__ float att[D_];
    __shared__ float hv[MID_];
    __shared__ float red2[2];
    __shared__ float cnt_s;

    {
        const float4* pp = (const float4*)(PP + ((size_t)(b * H_) + h) * E_);
        const float4* p2 = (const float4*)(P2 + (size_t)b * E_);
        ((float4*)pooled)[2 * t]     = pp[2 * t];
        ((float4*)pooled)[2 * t + 1] = pp[2 * t + 1];
        ((float4*)pool2)[2 * t]      = p2[2 * t];
        ((float4*)pool2)[2 * t + 1]  = p2[2 * t + 1];

        int ci = 0;
        #pragma unroll
        for (int i = 0; i < 8; ++i) ci += mask[b * N_ + t + i * 128];
        float cf = (float)ci;
        #pragma unroll
        for (int off = 32; off; off >>= 1) cf += __shfl_down(cf, off);
        if ((t & 63) == 0) red2[t >> 6] = cf;
    }
    __syncthreads();
    if (t == 0) cnt_s = red2[0] + red2[1];
    __syncthreads();
    const float cnt = cnt_s;
    const float ss = ssumg[bh];

    const int d = t;
    const float4* wv = (const float4*)(Wv + ((size_t)(h * D_ + d)) * E_);
    float accA = 0.f, accV = 0.f;
    for (int i = 0; i < 256; ++i) {
        float4 w = wv[i];
        int e = i * 4;
        accA += pooled[e] * w.x + pooled[e + 1] * w.y + pooled[e + 2] * w.z + pooled[e + 3] * w.w;
        accV += pool2[e]  * w.x + pool2[e + 1]  * w.y + pool2[e + 2]  * w.z + pool2[e + 3]  * w.w;
    }
    const float bvd = bv[h * D_ + d];
    att[d] = accA + ss * bvd;
    __syncthreads();

    if (t < MID_) {
        float a = bb[t];
        for (int d2 = 0; d2 < D_; ++d2) a += att[d2] * Wb[t * D_ + d2];
        hv[t] = fmaxf(a, 0.f);
    }
    __syncthreads();

    float z = bl2[d];
    #pragma unroll
    for (int m = 0; m < MID_; ++m) z += hv[m] * Wl2[d * MID_ + m];
    float alphac = 1.f / (1.f + expf(-z));
    float v2a = accV / cnt + bvd;
    out[(size_t)b * E_ + h * D_ + d] = value1[(size_t)b * E_ + h * D_ + d] * v2a * alphac;
}

// ---------------------------------------------------------------------------
extern "C" void kernel_launch(void* const* d_in, const int* in_sizes, int n_in,
                              void* d_out, int out_size, void* d_ws, size_t ws_size,
                              hipStream_t stream)
{
    const float* query  = (const float*)d_in[0];
    const float* key    = (const float*)d_in[1];
    const int*   mask   = (const int*)d_in[2];
    const float* value1 = (const float*)d_in[3];
    const float* value2 = (const float*)d_in[4];
    const float* Wq  = (const float*)d_in[5];
    const float* bq  = (const float*)d_in[6];
    const float* Wk  = (const float*)d_in[7];
    const float* bk  = (const float*)d_in[8];
    const float* Wv  = (const float*)d_in[9];
    const float* bv  = (const float*)d_in[10];
    const float* Wb  = (const float*)d_in[11];
    const float* bb  = (const float*)d_in[12];
    // d_in[13] = Wl, d_in[14] = bl: eliminated (softmax over identical values = mask/cnt)
    const float* Wl2 = (const float*)d_in[15];
    const float* bl2 = (const float*)d_in[16];
    float* out = (float*)d_out;

    // workspace layout (bytes), total ~2.13 MB
    char* ws = (char*)d_ws;
    const size_t OFF_P2 = (size_t)B_ * H_ * E_ * 4;     // PP: 1 MB
    const size_t OFF_SS = OFF_P2 + (size_t)B_ * E_ * 4; // P2: 128 KB
    const size_t OFF_QB = OFF_SS + 1024;                // ssum: 1 KB
    const size_t OFF_QK = OFF_QB + 1024;                // qb: 1 KB
    float* PP   = (float*)(ws);
    float* P2   = (float*)(ws + OFF_P2);
    float* ssum = (float*)(ws + OFF_SS);
    float* qb   = (float*)(ws + OFF_QB);
    float* qk   = (float*)(ws + OFF_QK);                // 1 MB

    // zero the atomic-accumulated region (PP, P2, ssum); stream-ordered, capture-safe
    hipMemsetAsync(d_ws, 0, OFF_QB, stream);

    hipLaunchKernelGGL(k_qkproj, dim3(B_ * H_), dim3(256), 0, stream,
                       query, Wq, bq, Wk, bk, qk, qb);
    hipLaunchKernelGGL(k_scorepool, dim3(NT_, B_), dim3(256), 0, stream,
                       key, qk, qb, PP, ssum);
    hipLaunchKernelGGL(k_pool_v2, dim3(NS2_, B_), dim3(256), 0, stream,
                       value2, mask, P2);
    hipLaunchKernelGGL(k_final, dim3(B_ * H_), dim3(128), 0, stream,
                       PP, P2, ssum, mask, Wv, bv, Wb, bb, Wl2, bl2, value1, out);
}